// Round 16
// baseline (1348.973 us; speedup 1.0000x reference)
//
#include <hip/hip_runtime.h>

#define BB 256      // batch
#define TT 2048     // timesteps
#define DD 32       // obs dim
#define HH 64       // hidden
#define GG 256      // 4*H gates
#define OB 8        // steps per output burst
#define LOG2E 1.44269504088896f

#if __has_builtin(__builtin_amdgcn_exp2f)
#define EXP2F(x) __builtin_amdgcn_exp2f(x)
#else
#define EXP2F(x) exp2f(x)
#endif

// sigmoid taking a pre-scaled argument y = log2(e)*x: rcp(1 + 2^-y)
__device__ __forceinline__ float sig_e2(float y) {
    return __builtin_amdgcn_rcpf(1.0f + EXP2F(-y));
}
__device__ __forceinline__ float rdlane(float v, int k) {
    return __uint_as_float(__builtin_amdgcn_readlane(__float_as_uint(v), k));
}
// LDS-only barrier: drain lgkmcnt, leave global loads/stores in flight.
__device__ __forceinline__ void lds_barrier() {
    asm volatile("s_waitcnt lgkmcnt(0)" ::: "memory");
    __builtin_amdgcn_s_barrier();
    asm volatile("" ::: "memory");
}

// PAIRED K-SPLIT: 128 blocks x 512 threads. Waves 0-3 run batch element
// 2b, waves 4-7 run element 2b+1 -- two INDEPENDENT R14 pipelines whose
// chains interleave on the shared SIMDs (2 waves/SIMD, uncorrelated
// stalls). Within each half: wave w computes, for all 4 gates of unit l,
// the partial pre-activation over its K-slice; exchange = 1 ds_write_b128
// + 4 ds_read_b128; all 4 activations ILP-parallel post-read; h/c are
// in-register replicas. Weights pre-scaled by log2(e) -> raw v_exp_f32.
__global__ __launch_bounds__(512, 1) void lstm_pair_kernel(
    const float* __restrict__ y,    // [B, T, D]
    const float* __restrict__ Wx,   // [D, 4H]
    const float* __restrict__ Wh,   // [H, 4H]
    const float* __restrict__ b,    // [4H]
    float* __restrict__ out)        // [B, T, H]
{
    const int tid = threadIdx.x;      // 0..511
    const int wv  = tid >> 6;         // wave 0..7
    const int eh  = wv >> 2;          // element half 0/1
    const int w   = wv & 3;           // K-slice wave within half
    const int l   = tid & 63;         // lane = hidden unit
    const int elem = blockIdx.x * 2 + eh;
    const int kb  = 16 * w;           // h K-slice base

    __shared__ float4 gbuf[2][2][4][HH];   // [buf][elem][wave][unit] (16 KB)
    __shared__ float  obuf[2][2][OB][HH];  // [buf][elem][step][unit] (8 KB)

    // ---- per-lane weight slices, pre-scaled by log2(e)
    float wh[4][16];                  // Wh rows kb..kb+15, cols g*64+l
#pragma unroll
    for (int g = 0; g < 4; ++g)
#pragma unroll
        for (int k = 0; k < 16; ++k)
            wh[g][k] = Wh[(kb + k) * GG + g * HH + l] * LOG2E;
    float wx[4][8];                   // Wx rows 8w..8w+7, cols g*64+l
#pragma unroll
    for (int g = 0; g < 4; ++g)
#pragma unroll
        for (int d = 0; d < 8; ++d)
            wx[g][d] = Wx[(8 * w + d) * GG + g * HH + l] * LOG2E;
    float bj[4];                      // bias: only wave 0 of each half
#pragma unroll
    for (int g = 0; g < 4; ++g) bj[g] = (w == 0) ? b[g * HH + l] * LOG2E : 0.0f;

    float c = 0.0f, h = 0.0f;         // lane l's replica of c[l], h[l]

    const float* ybase = y + (size_t)elem * (TT * DD) + 8 * w;
    float* obase = out + (size_t)elem * (TT * HH);

    // x slice (8 floats) double-buffered; accumulators carried across steps
    float4 xa[2], xb[2];
    float a0[4], a1[4];
    {
        // a <- bias + x(0)*Wx ; xa <- x(1)   (pre-activations in log2e scale)
        const float4* r0 = (const float4*)ybase;
        float4 x00 = r0[0], x01 = r0[1];
        const float* xf = (const float*)&x00;
        const float* xg = (const float*)&x01;
#pragma unroll
        for (int g = 0; g < 4; ++g) { a0[g] = bj[g]; a1[g] = 0.0f; }
#pragma unroll
        for (int d = 0; d < 4; ++d)
#pragma unroll
            for (int g = 0; g < 4; ++g) a0[g] = fmaf(xf[d], wx[g][d], a0[g]);
#pragma unroll
        for (int d = 0; d < 4; ++d)
#pragma unroll
            for (int g = 0; g < 4; ++g) a1[g] = fmaf(xg[d], wx[g][d + 4], a1[g]);
        const float4* r1 = (const float4*)(ybase + DD);
        xa[0] = r1[0]; xa[1] = r1[1];
    }
    __syncthreads();   // once at init

    // XC: x(TI+1) regs (consumed in shadows); XN: prefetch target x(TI+2).
#define STEP(XC, XN, BUFI, TI, TL)                                            \
    {                                                                         \
        /* 1. chain head: h-GEMV, 16 rdlane each feeding 4 gates */           \
        _Pragma("unroll")                                                     \
        for (int k = 0; k < 8; ++k) {                                         \
            const float hk = rdlane(h, kb + k);                               \
            _Pragma("unroll")                                                 \
            for (int g = 0; g < 4; ++g) a0[g] = fmaf(hk, wh[g][k], a0[g]);    \
        }                                                                     \
        _Pragma("unroll")                                                     \
        for (int k = 8; k < 16; ++k) {                                        \
            const float hk = rdlane(h, kb + k);                               \
            _Pragma("unroll")                                                 \
            for (int g = 0; g < 4; ++g) a1[g] = fmaf(hk, wh[g][k], a1[g]);    \
        }                                                                     \
        /* 2. fold + publish partials (single b128) */                        \
        float4 pw;                                                            \
        pw.x = a0[0] + a1[0]; pw.y = a0[1] + a1[1];                           \
        pw.z = a0[2] + a1[2]; pw.w = a0[3] + a1[3];                           \
        gbuf[BUFI][eh][w][l] = pw;                                            \
        /* 3. shadow-a (covers write-ack): acc re-init + x d0..3 + prefetch */\
        {                                                                     \
            const float* xf_ = (const float*)&XC[0];                          \
            _Pragma("unroll")                                                 \
            for (int g = 0; g < 4; ++g) a0[g] = bj[g];                        \
            _Pragma("unroll")                                                 \
            for (int d = 0; d < 4; ++d)                                       \
                _Pragma("unroll")                                             \
                for (int g = 0; g < 4; ++g)                                   \
                    a0[g] = fmaf(xf_[d], wx[g][d], a0[g]);                    \
        }                                                                     \
        {                                                                     \
            const int tn_ = ((TI) + 2 < TT) ? ((TI) + 2) : (TT - 1);          \
            const float4* nr_ = (const float4*)(ybase + (size_t)tn_ * DD);    \
            XN[0] = nr_[0]; XN[1] = nr_[1];                                   \
        }                                                                     \
        lds_barrier();                                                        \
        /* 4. reads issue; shadow-b (x d4..7) fills their latency */          \
        const float4 P0 = gbuf[BUFI][eh][0][l];                               \
        const float4 P1 = gbuf[BUFI][eh][1][l];                               \
        const float4 P2 = gbuf[BUFI][eh][2][l];                               \
        const float4 P3 = gbuf[BUFI][eh][3][l];                               \
        {                                                                     \
            const float* xg_ = (const float*)&XC[1];                          \
            _Pragma("unroll")                                                 \
            for (int g = 0; g < 4; ++g) a1[g] = 0.0f;                         \
            _Pragma("unroll")                                                 \
            for (int d = 0; d < 4; ++d)                                       \
                _Pragma("unroll")                                             \
                for (int g = 0; g < 4; ++g)                                   \
                    a1[g] = fmaf(xg_[d], wx[g][d + 4], a1[g]);                \
        }                                                                     \
        /* 5. sum partials; 4 activation chains ILP-parallel (log2e scale) */ \
        const float gi_ = (P0.x + P1.x) + (P2.x + P3.x);                      \
        const float gf_ = (P0.y + P1.y) + (P2.y + P3.y);                      \
        const float gg_ = (P0.z + P1.z) + (P2.z + P3.z);                      \
        const float go_ = (P0.w + P1.w) + (P2.w + P3.w);                      \
        const float i_ = sig_e2(gi_);                                         \
        const float f_ = sig_e2(gf_);                                         \
        const float g_ = fmaf(2.0f, sig_e2(2.0f * gg_), -1.0f);  /* tanh */   \
        const float o_ = sig_e2(go_);                                         \
        c = fmaf(f_, c, i_ * g_);                                             \
        /* tanh(c), c unscaled: 2^( -2*log2e*c ) */                           \
        h = o_ * fmaf(2.0f, __builtin_amdgcn_rcpf(                            \
                1.0f + EXP2F(c * (-2.0f * LOG2E))), -1.0f);                   \
        if (w == 0) obuf[obi][eh][TL][l] = h;                                 \
    }

    for (int t0 = 0; t0 < TT; t0 += OB) {
        const int obi = (t0 >> 3) & 1;
#pragma unroll
        for (int tp = 0; tp < OB; tp += 2) {
            STEP(xa, xb, 0, t0 + tp, tp)
            STEP(xb, xa, 1, t0 + tp + 1, tp + 1)
        }
        // publish obuf rows, then coalesced burst store (fire & forget)
        lds_barrier();
        {
            const int jj = tid & 255;
            const int e2 = tid >> 8;           // which element's obuf
            const int r  = jj >> 5;            // row 0..7
            const int ci = (jj & 31) * 2;      // col 0..62
            float* ob2 = out + (size_t)(blockIdx.x * 2 + e2) * (TT * HH);
            const float2 v = *(const float2*)&obuf[obi][e2][r][ci];
            *(float2*)&ob2[(size_t)(t0 + r) * HH + ci] = v;
        }
    }
#undef STEP
}

extern "C" void kernel_launch(void* const* d_in, const int* in_sizes, int n_in,
                              void* d_out, int out_size, void* d_ws, size_t ws_size,
                              hipStream_t stream) {
    const float* y  = (const float*)d_in[0];
    const float* Wx = (const float*)d_in[1];
    const float* Wh = (const float*)d_in[2];
    const float* b  = (const float*)d_in[3];
    float* out = (float*)d_out;

    lstm_pair_kernel<<<BB / 2, 512, 0, stream>>>(y, Wx, Wh, b, out);
}

// Round 17
// 1069.432 us; speedup vs baseline: 1.2614x; 1.2614x over previous
//
#include <hip/hip_runtime.h>

#define BB 256      // batch
#define TT 2048     // timesteps
#define DD 32       // obs dim
#define HH 64       // hidden
#define GG 256      // 4*H gates
#define OB 8        // steps per output burst
#define LOG2E 1.44269504088896f

typedef float f32x2 __attribute__((ext_vector_type(2)));
typedef float f32x4 __attribute__((ext_vector_type(4)));

// sigmoid taking a pre-scaled argument y = log2(e)*x: rcp(1 + 2^-y)
__device__ __forceinline__ float sig_e2(float y) {
    return __builtin_amdgcn_rcpf(1.0f + __builtin_exp2f(-y));
}
__device__ __forceinline__ float rdlane(float v, int k) {
    return __uint_as_float(__builtin_amdgcn_readlane(__float_as_uint(v), k));
}
// LDS-only barrier: drain lgkmcnt, leave global loads/stores in flight.
__device__ __forceinline__ void lds_barrier() {
    asm volatile("s_waitcnt lgkmcnt(0)" ::: "memory");
    __builtin_amdgcn_s_barrier();
    asm volatile("" ::: "memory");
}

// R14 K-split structure with PACKED f32 math on the chain:
//  - h-GEMV: two ILP chains live in the .x/.y halves of one f32x2 acc;
//    8 h-pairs (2 rdlane each) x 4 gates of v_pk_fma_f32 = 32 pk-FMA
//    (was 64 scalar FMA). Exact same fp32 arithmetic, reordered only.
//  - P-sums as f32x4 vector adds (pk-add emission).
//  - weights pre-scaled by log2(e): all 6 transcendentals use raw v_exp2.
// Exchange/shadow/burst layout identical to R14.
__global__ __launch_bounds__(256, 1) void lstm_pk_kernel(
    const float* __restrict__ y,    // [B, T, D]
    const float* __restrict__ Wx,   // [D, 4H]
    const float* __restrict__ Wh,   // [H, 4H]
    const float* __restrict__ b,    // [4H]
    float* __restrict__ out)        // [B, T, H]
{
    const int j = threadIdx.x;        // 0..255
    const int w = j >> 6;             // wave id = K-slice 0..3
    const int l = j & 63;             // lane = hidden unit
    const int batch = blockIdx.x;
    const int kb = 16 * w;            // h K-slice base

    __shared__ f32x4 gbuf[2][4][HH];      // [buf][wave][unit] partials (8 KB)
    __shared__ float obuf[2][OB][HH];     // output staging ring (4 KB)

    // ---- per-lane weight slices (coalesced; pre-scaled by log2e)
    f32x2 whp[4][8];                  // Wh row-pairs (kb+2m, kb+2m+1), col g*64+l
#pragma unroll
    for (int g = 0; g < 4; ++g)
#pragma unroll
        for (int m = 0; m < 8; ++m) {
            whp[g][m].x = Wh[(kb + 2 * m) * GG + g * HH + l] * LOG2E;
            whp[g][m].y = Wh[(kb + 2 * m + 1) * GG + g * HH + l] * LOG2E;
        }
    float wx[4][8];                   // Wx rows 8w..8w+7, cols g*64+l
#pragma unroll
    for (int g = 0; g < 4; ++g)
#pragma unroll
        for (int d = 0; d < 8; ++d)
            wx[g][d] = Wx[(8 * w + d) * GG + g * HH + l] * LOG2E;
    float bj[4];                      // bias: only wave 0 carries it
#pragma unroll
    for (int g = 0; g < 4; ++g) bj[g] = (w == 0) ? b[g * HH + l] * LOG2E : 0.0f;

    float c = 0.0f, h = 0.0f;         // lane l's replica of c[l], h[l]

    const float* ybase = y + (size_t)batch * (TT * DD) + 8 * w;
    float* obase = out + (size_t)batch * (TT * HH);

    // x slice (8 floats) double-buffered; packed accumulators carried
    float4 xa[2], xb[2];
    f32x2 ap[4];                      // .x / .y = the two ILP chains
    {
        // ap <- bias + x(0)*Wx ; xa <- x(1)
        const float4* r0 = (const float4*)ybase;
        float4 x00 = r0[0], x01 = r0[1];
        const float* xf = (const float*)&x00;
        const float* xg = (const float*)&x01;
#pragma unroll
        for (int g = 0; g < 4; ++g) { ap[g].x = bj[g]; ap[g].y = 0.0f; }
#pragma unroll
        for (int d = 0; d < 4; ++d)
#pragma unroll
            for (int g = 0; g < 4; ++g) ap[g].x = fmaf(xf[d], wx[g][d], ap[g].x);
#pragma unroll
        for (int d = 0; d < 4; ++d)
#pragma unroll
            for (int g = 0; g < 4; ++g) ap[g].y = fmaf(xg[d], wx[g][d + 4], ap[g].y);
        const float4* r1 = (const float4*)(ybase + DD);
        xa[0] = r1[0]; xa[1] = r1[1];
    }
    __syncthreads();   // once at init

    // XC: x(TI+1) regs (consumed in shadows); XN: prefetch target x(TI+2).
#define STEP(XC, XN, BUFI, TI, TL)                                            \
    {                                                                         \
        /* 1. chain head: packed h-GEMV, 8 h-pairs x 4 gates of pk-FMA */     \
        _Pragma("unroll")                                                     \
        for (int m = 0; m < 8; ++m) {                                         \
            f32x2 hp;                                                         \
            hp.x = rdlane(h, kb + 2 * m);                                     \
            hp.y = rdlane(h, kb + 2 * m + 1);                                 \
            _Pragma("unroll")                                                 \
            for (int g = 0; g < 4; ++g)                                       \
                ap[g] = __builtin_elementwise_fma(hp, whp[g][m], ap[g]);      \
        }                                                                     \
        /* 2. fold chains + publish partials (single b128 write) */           \
        f32x4 pw;                                                             \
        pw.x = ap[0].x + ap[0].y; pw.y = ap[1].x + ap[1].y;                   \
        pw.z = ap[2].x + ap[2].y; pw.w = ap[3].x + ap[3].y;                   \
        gbuf[BUFI][w][l] = pw;                                                \
        /* 3. shadow-a (covers write-ack): acc re-init + x d0..3 + prefetch */\
        {                                                                     \
            const float* xf_ = (const float*)&XC[0];                          \
            _Pragma("unroll")                                                 \
            for (int g = 0; g < 4; ++g) ap[g].x = bj[g];                      \
            _Pragma("unroll")                                                 \
            for (int d = 0; d < 4; ++d)                                       \
                _Pragma("unroll")                                             \
                for (int g = 0; g < 4; ++g)                                   \
                    ap[g].x = fmaf(xf_[d], wx[g][d], ap[g].x);                \
        }                                                                     \
        {                                                                     \
            const int tn_ = ((TI) + 2 < TT) ? ((TI) + 2) : (TT - 1);          \
            const float4* nr_ = (const float4*)(ybase + (size_t)tn_ * DD);    \
            XN[0] = nr_[0]; XN[1] = nr_[1];                                   \
        }                                                                     \
        lds_barrier();                                                        \
        /* 4. reads issue; shadow-b (x d4..7) fills their latency */          \
        const f32x4 P0 = gbuf[BUFI][0][l];                                    \
        const f32x4 P1 = gbuf[BUFI][1][l];                                    \
        const f32x4 P2 = gbuf[BUFI][2][l];                                    \
        const f32x4 P3 = gbuf[BUFI][3][l];                                    \
        {                                                                     \
            const float* xg_ = (const float*)&XC[1];                          \
            _Pragma("unroll")                                                 \
            for (int g = 0; g < 4; ++g) ap[g].y = 0.0f;                       \
            _Pragma("unroll")                                                 \
            for (int d = 0; d < 4; ++d)                                       \
                _Pragma("unroll")                                             \
                for (int g = 0; g < 4; ++g)                                   \
                    ap[g].y = fmaf(xg_[d], wx[g][d + 4], ap[g].y);            \
        }                                                                     \
        /* 5. packed partial sums; 4 activation chains ILP-parallel */        \
        const f32x4 PS = (P0 + P1) + (P2 + P3);                               \
        const float i_ = sig_e2(PS.x);                                        \
        const float f_ = sig_e2(PS.y);                                        \
        const float g_ = fmaf(2.0f, sig_e2(2.0f * PS.z), -1.0f);  /* tanh */  \
        const float o_ = sig_e2(PS.w);                                        \
        c = fmaf(f_, c, i_ * g_);                                             \
        h = o_ * fmaf(2.0f, __builtin_amdgcn_rcpf(                            \
                1.0f + __builtin_exp2f(c * (-2.0f * LOG2E))), -1.0f);         \
        if (w == 0) obuf[obi][TL][l] = h;                                     \
    }

    for (int t0 = 0; t0 < TT; t0 += OB) {
        const int obi = (t0 >> 3) & 1;
#pragma unroll
        for (int tp = 0; tp < OB; tp += 2) {
            STEP(xa, xb, 0, t0 + tp, tp)
            STEP(xb, xa, 1, t0 + tp + 1, tp + 1)
        }
        // publish w0's obuf rows, then coalesced burst store (fire & forget)
        lds_barrier();
        {
            const int r = j >> 5;              // row 0..7
            const int ci = (j & 31) * 2;       // col 0..62
            const float2 v = *(const float2*)&obuf[obi][r][ci];
            *(float2*)&obase[(size_t)(t0 + r) * HH + ci] = v;
        }
    }
#undef STEP
}

extern "C" void kernel_launch(void* const* d_in, const int* in_sizes, int n_in,
                              void* d_out, int out_size, void* d_ws, size_t ws_size,
                              hipStream_t stream) {
    const float* y  = (const float*)d_in[0];
    const float* Wx = (const float*)d_in[1];
    const float* Wh = (const float*)d_in[2];
    const float* b  = (const float*)d_in[3];
    float* out = (float*)d_out;

    lstm_pk_kernel<<<BB, GG, 0, stream>>>(y, Wx, Wh, b, out);
}